// Round 6
// baseline (420.451 us; speedup 1.0000x reference)
//
#include <hip/hip_runtime.h>
#include <math.h>

#define BB 64
#define NN 8732
#define CC 81
#define TR2 16                        // rows per wave-iteration
#define WIT 4                         // iterations per wave
#define WROWS (TR2 * WIT)             // 64 rows per wave
#define BROWS (WROWS * 4)             // 256 rows per block
#define CBX ((NN + BROWS - 1) / BROWS)  // 35 conf blocks per batch
#define LBX 5                         // loc blocks per batch
#define LSEG4 328                     // float4s per wave LDS segment (1312 floats)

// ---------------- init: zero per-b accumulators + output ----------------
__global__ void init_kernel(unsigned* acc, float* out) {
    int i = threadIdx.x;
    if (i < 4 * BB) acc[i] = 0u;   // num_pos[B], pos_sum[B], loc_cnt[B], loc_sum[B]
    if (i == 0) out[0] = 0.f;
}

__device__ __forceinline__ float4 ld4g(const float* __restrict__ p, size_t gf, size_t TOTF) {
    if (gf + 4 <= TOTF) return *(const float4*)(p + gf);
    float4 r; float* rp = (float*)&r;
    #pragma unroll
    for (int c = 0; c < 4; ++c) rp[c] = (gf + c < TOTF) ? p[gf + c] : 0.f;
    return r;
}

// ---------------- fused conf + loc, barrier-free conf path ----------------
__global__ __launch_bounds__(256) void fused_kernel(
        const float* __restrict__ pred_conf,
        const float* __restrict__ gt_conf,
        const float* __restrict__ pred_loc,
        const float* __restrict__ gt_loc,
        float* __restrict__ neg_loss,
        int* __restrict__ num_pos,
        float* __restrict__ pos_sum,
        float* __restrict__ loc_cnt,
        float* __restrict__ loc_sum) {
    const int b   = blockIdx.y;
    const int tid = threadIdx.x;

    if (blockIdx.x >= CBX) {
        // ================= loc part =================
        const int lb = blockIdx.x - CBX;
        const float4* pl = (const float4*)pred_loc;
        const float4* gl = (const float4*)gt_loc;
        float sum = 0.f, cnt = 0.f;
        #pragma unroll
        for (int j = 0; j < 8; ++j) {
            int n = lb * 2048 + j * 256 + tid;
            if (n < NN) {
                size_t idx = (size_t)b * NN + n;
                float4 p = pl[idx];
                float4 g = gl[idx];
                bool any = false;
                float pv[4] = {p.x, p.y, p.z, p.w};
                float gv[4] = {g.x, g.y, g.z, g.w};
                #pragma unroll
                for (int c = 0; c < 4; ++c) {
                    if (gv[c] != 0.f) {
                        any = true;
                        float d = fabsf(pv[c] - gv[c]);
                        sum += (d < 1.f) ? 0.5f * d * d : d - 0.5f;
                    }
                }
                if (any) cnt += 1.f;
            }
        }
        for (int o = 32; o; o >>= 1) {
            sum += __shfl_down(sum, o, 64);
            cnt += __shfl_down(cnt, o, 64);
        }
        if ((tid & 63) == 0) {
            atomicAdd(&loc_sum[b], sum);
            atomicAdd(&loc_cnt[b], cnt);
        }
        return;
    }

    // ================= conf part: wave-private LDS, no __syncthreads =================
    __shared__ float4 lbuf4[4][LSEG4];           // 20992 B

    const size_t TOTF = (size_t)BB * NN * CC;
    const int wave = tid >> 6;
    const int lane = tid & 63;
    const int q    = lane >> 2;                  // quad (row within tile)
    const int h    = lane & 3;                   // position within quad
    float*  lws = (float*)lbuf4[wave];
    float4* l4  = lbuf4[wave];

    const int rowB0 = blockIdx.x * BROWS + wave * WROWS;

    int   my_cnt = 0;
    float my_sum = 0.f;

    // ---- prologue: prefetch tile 0 ----
    float4 rv[6];
    float  gt0p = 1.f;
    int curB  = rowB0;
    int curNr = min(TR2, NN - curB);
    int curSh = 0, curT4 = 0;
    if (curNr > 0) {
        size_t seg = ((size_t)b * NN + curB) * CC;
        size_t a0  = seg & ~(size_t)3;
        curSh = (int)(seg - a0);
        curT4 = (curSh + curNr * CC + 3) >> 2;
        #pragma unroll
        for (int j = 0; j < 6; ++j) {
            int i = lane + 64 * j;
            if (i < curT4) rv[j] = ld4g(pred_conf, a0 + 4 * (size_t)i, TOTF);
        }
        if (q < curNr) gt0p = gt_conf[((size_t)b * NN + curB + q) * CC];
    }

    for (int it = 0; it < WIT; ++it) {
        const int   c_rowB = curB, c_nr = curNr, c_sh = curSh, c_t4 = curT4;
        const float c_gt0  = gt0p;
        if (c_nr <= 0) break;

        // ---- ds_write staged tile (waits vmcnt for rv; issued a full iter ago) ----
        #pragma unroll
        for (int j = 0; j < 6; ++j) {
            int i = lane + 64 * j;
            if (i < c_t4) l4[i] = rv[j];
        }

        // ---- prefetch next tile: loads fly during compute below ----
        const int nB  = rowB0 + (it + 1) * TR2;
        const int nNr = (it + 1 < WIT) ? min(TR2, NN - nB) : 0;
        if (nNr > 0) {
            size_t seg = ((size_t)b * NN + nB) * CC;
            size_t a0  = seg & ~(size_t)3;
            curSh = (int)(seg - a0);
            curT4 = (curSh + nNr * CC + 3) >> 2;
            #pragma unroll
            for (int j = 0; j < 6; ++j) {
                int i = lane + 64 * j;
                if (i < curT4) rv[j] = ld4g(pred_conf, a0 + 4 * (size_t)i, TOTF);
            }
            gt0p = (q < nNr) ? gt_conf[((size_t)b * NN + nB + q) * CC] : 1.f;
        }
        curB = nB; curNr = nNr;

        // ---- compute current tile: quad per row, within-wave only ----
        if (q < c_nr) {
            const int c0 = h * 20 + (h > 0 ? 1 : 0);
            const int nc = (h == 0) ? 21 : 20;
            const float* row = lws + c_sh + q * CC;
            const size_t gbase = ((size_t)b * NN + c_rowB + q) * CC;

            float v[21];
            #pragma unroll
            for (int j = 0; j < 21; ++j)
                v[j] = (j < nc) ? row[c0 + j] : -1e30f;

            float m = v[0];
            #pragma unroll
            for (int j = 1; j < 21; ++j) m = fmaxf(m, v[j]);
            m = fmaxf(m, __shfl_xor(m, 1, 64));
            m = fmaxf(m, __shfl_xor(m, 2, 64));

            float e = 0.f;
            #pragma unroll
            for (int j = 0; j < 21; ++j) e += __expf(v[j] - m);   // pad -> exp -> 0
            e += __shfl_xor(e, 1, 64);
            e += __shfl_xor(e, 2, 64);

            const bool pos = (c_gt0 == 0.f);   // background prob 0 => positive prior
            float x_sel = v[0];                // row[0] valid on h==0 (writer lane)
            if (pos) {
                float d = 0.f;
                #pragma unroll
                for (int j = 0; j < 21; ++j)
                    if (j < nc) d += gt_conf[gbase + c0 + j] * v[j];
                d += __shfl_xor(d, 1, 64);
                d += __shfl_xor(d, 2, 64);
                x_sel = d;                     // pred at one-hot label
            }

            const float loss = m + __logf(e) - x_sel;
            if (h == 0) {
                neg_loss[(size_t)b * NN + c_rowB + q] = pos ? 0.f : loss;
                if (pos) { my_cnt++; my_sum += loss; }
            }
        }
    }

    // ---- wave-level reduction over quad leaders (lanes 0,4,...,60) ----
    #pragma unroll
    for (int off = 4; off < 64; off <<= 1) {
        my_sum += __shfl_down(my_sum, off, 64);
        my_cnt += __shfl_down(my_cnt, off, 64);
    }
    if (lane == 0 && my_cnt) {
        atomicAdd(&num_pos[b], my_cnt);
        atomicAdd(&pos_sum[b], my_sum);
    }
}

// ---------------- per-batch radix select + finalize (atomic mean) ----------------
__global__ __launch_bounds__(256) void select_kernel(
        const float* __restrict__ neg_loss,
        const int*   __restrict__ num_pos,
        const float* __restrict__ pos_sum,
        const float* __restrict__ loc_cnt,
        const float* __restrict__ loc_sum,
        float* __restrict__ out) {
    const int b    = blockIdx.x;
    const int tid  = threadIdx.x;
    const int lane = tid & 63;
    __shared__ unsigned vals[NN];        // 34928 B
    __shared__ unsigned hist[256];
    __shared__ unsigned sh_prefix, sh_r;
    __shared__ float    s_part[4];

    #pragma unroll 4
    for (int i = tid; i < NN; i += 256)
        vals[i] = __float_as_uint(neg_loss[(size_t)b * NN + i]);

    const int np = num_pos[b];
    const int k  = min(3 * np, NN - 1);  // clip(int(num_neg), 0, N-1)
    if (tid == 0) { sh_prefix = 0u; sh_r = (unsigned)k; }
    __syncthreads();

    unsigned prefix_mask = 0u;
    for (int p = 3; p >= 0; --p) {
        const unsigned pref = sh_prefix;
        const unsigned r    = sh_r;
        hist[tid] = 0u;
        __syncthreads();

        // ballot-aggregated histogram: one atomic per distinct bin per wave
        for (int i0 = 0; i0 < NN; i0 += 256) {
            const int i = i0 + tid;
            const bool act = (i < NN) && ((vals[i] & prefix_mask) == pref);
            const unsigned v   = act ? vals[i] : 0u;
            const unsigned bin = (v >> (8 * p)) & 255u;
            unsigned long long mm = __ballot(act);
            #pragma unroll
            for (int bit = 0; bit < 8; ++bit) {
                unsigned long long s = __ballot(act && ((bin >> bit) & 1u));
                mm &= ((bin >> bit) & 1u) ? s : ~s;
            }
            if (act && ((mm & ((1ull << lane) - 1ull)) == 0ull))
                atomicAdd(&hist[bin], (unsigned)__popcll(mm));
        }
        __syncthreads();

        // wave-0 suffix scan over 256 bins (4 bins/lane) + bin pick
        if (tid < 64) {
            const unsigned h0 = hist[4 * tid + 0];
            const unsigned h1 = hist[4 * tid + 1];
            const unsigned h2 = hist[4 * tid + 2];
            const unsigned h3 = hist[4 * tid + 3];
            unsigned T = h0 + h1 + h2 + h3;
            #pragma unroll
            for (int off = 1; off < 64; off <<= 1) {
                unsigned t2 = __shfl_down(T, off, 64);
                if (tid + off < 64) T += t2;
            }
            unsigned Tn = __shfl_down(T, 1, 64);
            if (tid == 63) Tn = 0u;
            const unsigned S4 = Tn, S3 = S4 + h3, S2 = S3 + h2, S1 = S2 + h1, S0 = S1 + h0;
            int bin = -1; unsigned Slo = 0u;
            if      (S1 <= r && r < S0) { bin = 4 * tid + 0; Slo = S1; }
            else if (S2 <= r && r < S1) { bin = 4 * tid + 1; Slo = S2; }
            else if (S3 <= r && r < S2) { bin = 4 * tid + 2; Slo = S3; }
            else if (S4 <= r && r < S3) { bin = 4 * tid + 3; Slo = S4; }
            if (bin >= 0) {
                sh_r = r - Slo;
                sh_prefix = pref | ((unsigned)bin << (8 * p));
            }
        }
        __syncthreads();
        prefix_mask |= 0xFFu << (8 * p);
    }

    const float thresh = __uint_as_float(sh_prefix);   // exact (k+1)-th largest
    float s = 0.f;
    #pragma unroll 4
    for (int i = tid; i < NN; i += 256) {
        float v = __uint_as_float(vals[i]);
        if (v > thresh) s += v;                        // strict >, matches reference
    }
    for (int o = 32; o; o >>= 1) s += __shfl_down(s, o, 64);
    if (lane == 0) s_part[tid >> 6] = s;
    __syncthreads();
    if (tid == 0) {
        float neg_sum = s_part[0] + s_part[1] + s_part[2] + s_part[3];
        float npf = (float)np;
        float res = pos_sum[b] / npf + neg_sum / (3.0f * npf) + loc_sum[b] / loc_cnt[b];
        atomicAdd(out, res * (1.0f / BB));
    }
}

extern "C" void kernel_launch(void* const* d_in, const int* in_sizes, int n_in,
                              void* d_out, int out_size, void* d_ws, size_t ws_size,
                              hipStream_t stream) {
    const float* pred_conf = (const float*)d_in[0];
    const float* pred_loc  = (const float*)d_in[1];
    const float* gt_conf   = (const float*)d_in[2];
    const float* gt_loc    = (const float*)d_in[3];

    float* neg      = (float*)d_ws;                 // B*N floats
    int*   num_pos  = (int*)(neg + (size_t)BB * NN);
    float* pos_sum  = (float*)(num_pos + BB);
    float* loc_cnt  = pos_sum + BB;
    float* loc_sum  = loc_cnt + BB;

    init_kernel<<<1, 256, 0, stream>>>((unsigned*)num_pos, (float*)d_out);

    dim3 fgrid(CBX + LBX, BB);                      // 40 x 64
    fused_kernel<<<fgrid, 256, 0, stream>>>(pred_conf, gt_conf, pred_loc, gt_loc,
                                            neg, num_pos, pos_sum, loc_cnt, loc_sum);

    select_kernel<<<BB, 256, 0, stream>>>(neg, num_pos, pos_sum, loc_cnt, loc_sum,
                                          (float*)d_out);
}